// Round 10
// baseline (207.667 us; speedup 1.0000x reference)
//
#include <hip/hip_runtime.h>
#include <stdint.h>

#define NCH   30                   // channels per cell (cell = 120 B)
#define TPB   256                  // 4 waves per block
#define TILE  64                   // cells per tile
#define TW    (TILE * NCH)         // 1920 floats per array per tile
#define TF4   (TW / 4)             // 480 float4 chunks per array per tile
#define NBLK  1536                 // 6 blocks/CU (23.2 KB LDS) * 256 CUs

__device__ __forceinline__ float iou_f(float x1, float y1, float w1, float h1,
                                       float x2, float y2, float w2, float h2) {
    float l1 = x1 - 0.5f * w1, r1 = x1 + 0.5f * w1;
    float t1 = y1 - 0.5f * h1, b1 = y1 + 0.5f * h1;
    float l2 = x2 - 0.5f * w2, r2 = x2 + 0.5f * w2;
    float t2 = y2 - 0.5f * h2, b2 = y2 + 0.5f * h2;
    float in_h = fminf(b1, b2) - fmaxf(t1, t2);
    float in_w = fminf(r1, r2) - fmaxf(l1, l2);
    float inter = (in_h < 0.f || in_w < 0.f) ? 0.f : in_h * in_w;
    float a1 = (b1 - t1) * (r1 - l1);
    float a2 = (b2 - t2) * (r2 - l2);
    return inter / (a1 + a2 - inter);
}

// Bit-gated cell loss: caller guarantees mask==1.0, so no mask multiply.
// Reads pp[0..29] and lp[1..29] — all chunks covering this cell are staged.
__device__ __forceinline__ void cell_loss_nm(const float* __restrict__ pp,
                                             const float* __restrict__ lp,
                                             float& v0, float& v1, float& v2,
                                             float& v3, float& v4) {
    const float2 l01 = *(const float2*)(lp);        // -, gx
    const float2 l23 = *(const float2*)(lp + 2);    // gy, gw
    const float2 l45 = *(const float2*)(lp + 4);    // gh, -
    const float gx = l01.y, gy = l23.x, gw = l23.y, gh = l45.x;

    const float2 p01 = *(const float2*)(pp);        // -, b1x
    const float2 p23 = *(const float2*)(pp + 2);    // b1y, b1w
    const float2 p45 = *(const float2*)(pp + 4);    // b1h, -
    const float2 p67 = *(const float2*)(pp + 6);    // b2x, b2y
    const float2 p89 = *(const float2*)(pp + 8);    // b2w, b2h

    const float i1 = iou_f(p01.y, p23.x, p23.y, p45.x, gx, gy, gw, gh);
    const float i2 = iou_f(p67.x, p67.y, p89.x, p89.y, gx, gy, gw, gh);
    const bool best = (i1 >= i2);
    const float sx = best ? p01.y : p67.x;
    const float sy = best ? p23.x : p67.y;
    const float sw = best ? p23.y : p89.x;
    const float sh = best ? p45.x : p89.y;
    const float imax = best ? i1 : i2;
    const float imin = best ? i2 : i1;

    const float center = 5.f * ((sx - gx) * (sx - gx) + (sy - gy) * (sy - gy));
    const float dw = sqrtf(sw) - sqrtf(gw);
    const float dh = sqrtf(sh) - sqrtf(gh);
    const float wh = 5.f * (dw * dw + dh * dh);

    float cls = 0.f;
#pragma unroll
    for (int k = 0; k < 10; ++k) {                  // channels 10..29
        const float2 pd = *(const float2*)(pp + 10 + 2 * k);
        const float2 ld = *(const float2*)(lp + 10 + 2 * k);
        const float dx = pd.x - ld.x;
        const float dy = pd.y - ld.y;
        cls += dx * dx + dy * dy;
    }

    v0 += center;
    v1 += wh;
    v2 += imax;
    v3 += imin;
    v4 += cls;
}

// Full-mask variant for the (never-taken) global-memory tail path.
__device__ __forceinline__ void cell_loss(const float* __restrict__ pp,
                                          const float* __restrict__ lp,
                                          float& v0, float& v1, float& v2,
                                          float& v3, float& v4) {
    const float mask = lp[0];
    if (mask == 0.f) return;
    float a = 0.f, b = 0.f, c = 0.f, d = 0.f, e = 0.f;
    cell_loss_nm(pp, lp, a, b, c, d, e);
    v0 += a * mask; v1 += b * mask; v2 += c * mask; v3 += d * mask; v4 += e * mask;
}

// Three-stage pipelined, fully predicated staging:
//   - scalar ch0 "discovery" of tile t+2NB (wave 0: 64 x 4 B) -> ballot ->
//     bits, two tiles ahead of use.
//   - lab(t+NB) staged PREDICATED by bits(t+NB): only chunks covering in-mask
//     cells (~31% of the label stream; rest never read).
//   - pred(t) staged PREDICATED by bits(t) (as in R8).
//   - compute is bit-gated; mask==1.0 exactly, so no mask multiply.
// Requested bytes ~63 MB vs R8's ~130 MB. 2 syncs/iter.
__global__ __launch_bounds__(TPB) void yolo_partial(const float* __restrict__ pred,
                                                    const float* __restrict__ lab,
                                                    float* __restrict__ partial,
                                                    int n_cells) {
    __shared__ float sp[TW];                 // pred tile (7.68 KB)
    __shared__ float sl[2][TW];              // lab tiles cur/nxt (15.36 KB)
    __shared__ unsigned long long sbits[2];
    __shared__ float red[5][TPB / 64];

    const int tid  = threadIdx.x;
    const int wave = tid >> 6;
    const int lane = tid & 63;
    const int bid  = blockIdx.x;
    const int NB   = gridDim.x;
    const int nt   = n_cells / TILE;         // 12544 full tiles

    // This thread's two float4-chunk indices within a 480-chunk array tile.
    const int  idx0 = tid;                   // < 480 always (tid < 256)
    const int  idx1 = TPB + tid;             // < 480 iff tid < 224
    const bool has1 = (idx1 < TF4);

    // Chunk -> covering-cell ids (compile-time divide -> magic mul).
    const int c00 = (4 * idx0) / NCH, c01 = (4 * idx0 + 3) / NCH;
    const int c10 = has1 ? (4 * idx1) / NCH : 0;
    const int c11 = has1 ? (4 * idx1 + 3) / NCH : 0;

    float v0 = 0.f, v1 = 0.f, v2 = 0.f, v3 = 0.f, v4 = 0.f;

    int cur = 0;
    unsigned long long bits_cur = 0, bits_next = 0;

    if (bid < nt) {
        // ---- prologue: discover masks of tiles bid and bid+NB ----
        {
            const float m0 = (tid < TILE)
                ? lab[(size_t)bid * TW + (size_t)tid * NCH] : 0.f;
            const float m1 = (tid < TILE && bid + NB < nt)
                ? lab[(size_t)(bid + NB) * TW + (size_t)tid * NCH] : 0.f;
            const unsigned long long b0 = __ballot(m0 != 0.f);
            const unsigned long long b1 = __ballot(m1 != 0.f);
            if (tid == 0) { sbits[0] = b0; sbits[1] = b1; }
        }
        __syncthreads();
        bits_cur  = sbits[0];
        bits_next = sbits[1];

        // ---- stage lab(bid) predicated by bits_cur (sync happens in-loop) ----
        {
            const size_t gbase = (size_t)bid * TW;
            const bool n0 = (((bits_cur >> c00) | (bits_cur >> c01)) & 1ull);
            const bool n1 = has1 && (((bits_cur >> c10) | (bits_cur >> c11)) & 1ull);
            if (n0) *(float4*)(&sl[0][idx0 * 4]) =
                        *(const float4*)(lab + gbase + (size_t)idx0 * 4);
            if (n1) *(float4*)(&sl[0][idx1 * 4]) =
                        *(const float4*)(lab + gbase + (size_t)idx1 * 4);
        }

        for (int t = bid; t < nt; t += NB) {
            const int  nxt   = cur ^ 1;
            const bool have1 = (t + NB < nt);
            const bool have2 = (t + 2 * NB < nt);
            const size_t gbase = (size_t)t * TW;

            // ---- issue ALL loads for this iteration, dependency-free ----
            float4 p0, p1, l0, l1;
            const bool pn0 = (((bits_cur >> c00) | (bits_cur >> c01)) & 1ull);
            const bool pn1 = has1 && (((bits_cur >> c10) | (bits_cur >> c11)) & 1ull);
            if (pn0) p0 = *(const float4*)(pred + gbase + (size_t)idx0 * 4);
            if (pn1) p1 = *(const float4*)(pred + gbase + (size_t)idx1 * 4);

            bool ln0 = false, ln1 = false;
            if (have1) {
                const size_t nbase = (size_t)(t + NB) * TW;
                ln0 = (((bits_next >> c00) | (bits_next >> c01)) & 1ull);
                ln1 = has1 && (((bits_next >> c10) | (bits_next >> c11)) & 1ull);
                if (ln0) l0 = *(const float4*)(lab + nbase + (size_t)idx0 * 4);
                if (ln1) l1 = *(const float4*)(lab + nbase + (size_t)idx1 * 4);
            }

            // discovery: ch0 of tile t+2NB, 4 B per lane of wave 0
            const float md = (tid < TILE && have2)
                ? lab[(size_t)(t + 2 * NB) * TW + (size_t)tid * NCH] : 0.f;

            // ---- spill to LDS (compiler inserts precise vmcnt waits) ----
            if (pn0) *(float4*)(&sp[idx0 * 4]) = p0;
            if (pn1) *(float4*)(&sp[idx1 * 4]) = p1;
            if (ln0) *(float4*)(&sl[nxt][idx0 * 4]) = l0;
            if (ln1) *(float4*)(&sl[nxt][idx1 * 4]) = l1;
            __syncthreads();

            // ---- compute tile t: bit-gated, one cell per lane of wave 0 ----
            if (tid < TILE && ((bits_cur >> tid) & 1ull))
                cell_loss_nm(sp + tid * NCH, &sl[cur][tid * NCH],
                             v0, v1, v2, v3, v4);

            // ---- ballot the discovered masks (t+2NB) and broadcast ----
            const unsigned long long bd = __ballot(md != 0.f);
            if (tid == 0) sbits[0] = bd;
            __syncthreads();
            bits_cur  = bits_next;
            bits_next = sbits[0];
            cur = nxt;
        }
    }

    // Remainder cells — direct from global (never taken: 802816 % 64 == 0).
    const int rem_start = nt * TILE;
    if (bid == 0 && rem_start < n_cells) {
        for (int c = rem_start + tid; c < n_cells; c += TPB) {
            cell_loss(pred + (size_t)c * NCH, lab + (size_t)c * NCH,
                      v0, v1, v2, v3, v4);
        }
    }

    // ---- block reduction ----
#pragma unroll
    for (int off = 32; off > 0; off >>= 1) {
        v0 += __shfl_down(v0, off);
        v1 += __shfl_down(v1, off);
        v2 += __shfl_down(v2, off);
        v3 += __shfl_down(v3, off);
        v4 += __shfl_down(v4, off);
    }
    if (lane == 0) {
        red[0][wave] = v0;
        red[1][wave] = v1;
        red[2][wave] = v2;
        red[3][wave] = v3;
        red[4][wave] = v4;
    }
    __syncthreads();
    if (tid < 5) {
        float sacc = 0.f;
#pragma unroll
        for (int w = 0; w < TPB / 64; ++w) sacc += red[tid][w];
        partial[(size_t)bid * 5 + tid] = sacc;
    }
}

// Reduce n_blocks x 5 partials -> out[0..4]. One block.
__global__ __launch_bounds__(256) void final_reduce(const float* __restrict__ partial,
                                                    float* __restrict__ out,
                                                    int n_blocks) {
    __shared__ float red[5][4];
    const int tid = threadIdx.x;
    float v0 = 0.f, v1 = 0.f, v2 = 0.f, v3 = 0.f, v4 = 0.f;
    for (int b = tid; b < n_blocks; b += 256) {
        const float* p = partial + (size_t)b * 5;
        v0 += p[0]; v1 += p[1]; v2 += p[2]; v3 += p[3]; v4 += p[4];
    }
#pragma unroll
    for (int off = 32; off > 0; off >>= 1) {
        v0 += __shfl_down(v0, off);
        v1 += __shfl_down(v1, off);
        v2 += __shfl_down(v2, off);
        v3 += __shfl_down(v3, off);
        v4 += __shfl_down(v4, off);
    }
    const int wave = tid >> 6;
    const int lane = tid & 63;
    if (lane == 0) {
        red[0][wave] = v0;
        red[1][wave] = v1;
        red[2][wave] = v2;
        red[3][wave] = v3;
        red[4][wave] = v4;
    }
    __syncthreads();
    if (tid < 5) {
        float sacc = 0.f;
#pragma unroll
        for (int w = 0; w < 4; ++w) sacc += red[tid][w];
        out[tid] = sacc;
    }
}

extern "C" void kernel_launch(void* const* d_in, const int* in_sizes, int n_in,
                              void* d_out, int out_size, void* d_ws, size_t ws_size,
                              hipStream_t stream) {
    const float* pred = (const float*)d_in[0];
    const float* lab  = (const float*)d_in[1];
    float* out = (float*)d_out;
    float* partial = (float*)d_ws;                 // 1536*5*4 = 30,720 B

    const int n_cells = in_sizes[0] / NCH;         // 802816

    hipLaunchKernelGGL(yolo_partial, dim3(NBLK), dim3(TPB), 0, stream,
                       pred, lab, partial, n_cells);
    hipLaunchKernelGGL(final_reduce, dim3(1), dim3(256), 0, stream,
                       partial, out, NBLK);
}

// Round 11
// 201.692 us; speedup vs baseline: 1.0296x; 1.0296x over previous
//
#include <hip/hip_runtime.h>
#include <stdint.h>

#define NCH   30                   // channels per cell (cell = 120 B)
#define TPB   256                  // 4 waves per block
#define TILE  64                   // cells per tile
#define TW    (TILE * NCH)         // 1920 floats per array per tile
#define TF4   (TW / 4)             // 480 float4 chunks per array per tile
#define NBLK  1536                 // 6 blocks/CU (23.2 KB LDS) * 256 CUs

__device__ __forceinline__ float iou_f(float x1, float y1, float w1, float h1,
                                       float x2, float y2, float w2, float h2) {
    float l1 = x1 - 0.5f * w1, r1 = x1 + 0.5f * w1;
    float t1 = y1 - 0.5f * h1, b1 = y1 + 0.5f * h1;
    float l2 = x2 - 0.5f * w2, r2 = x2 + 0.5f * w2;
    float t2 = y2 - 0.5f * h2, b2 = y2 + 0.5f * h2;
    float in_h = fminf(b1, b2) - fmaxf(t1, t2);
    float in_w = fminf(r1, r2) - fmaxf(l1, l2);
    float inter = (in_h < 0.f || in_w < 0.f) ? 0.f : in_h * in_w;
    float a1 = (b1 - t1) * (r1 - l1);
    float a2 = (b2 - t2) * (r2 - l2);
    return inter / (a1 + a2 - inter);
}

// Compute the 5 loss terms for the cell at pp/lp, accumulate.
// Masked-out lanes return after reading only lp[0..1] (always-staged chunk).
__device__ __forceinline__ void cell_loss(const float* __restrict__ pp,
                                          const float* __restrict__ lp,
                                          float& v0, float& v1, float& v2,
                                          float& v3, float& v4) {
    const float2 l01 = *(const float2*)(lp);        // mask, gx
    const float mask = l01.x;
    if (mask == 0.f) return;

    const float2 l23 = *(const float2*)(lp + 2);    // gy, gw
    const float2 l45 = *(const float2*)(lp + 4);    // gh, -
    const float gx = l01.y, gy = l23.x, gw = l23.y, gh = l45.x;

    const float2 p01 = *(const float2*)(pp);        // -, b1x
    const float2 p23 = *(const float2*)(pp + 2);    // b1y, b1w
    const float2 p45 = *(const float2*)(pp + 4);    // b1h, -
    const float2 p67 = *(const float2*)(pp + 6);    // b2x, b2y
    const float2 p89 = *(const float2*)(pp + 8);    // b2w, b2h

    const float i1 = iou_f(p01.y, p23.x, p23.y, p45.x, gx, gy, gw, gh);
    const float i2 = iou_f(p67.x, p67.y, p89.x, p89.y, gx, gy, gw, gh);
    const bool best = (i1 >= i2);
    const float sx = best ? p01.y : p67.x;
    const float sy = best ? p23.x : p67.y;
    const float sw = best ? p23.y : p89.x;
    const float sh = best ? p45.x : p89.y;
    const float imax = best ? i1 : i2;
    const float imin = best ? i2 : i1;

    const float center = 5.f * ((sx - gx) * (sx - gx) + (sy - gy) * (sy - gy));
    const float dw = sqrtf(sw) - sqrtf(gw);
    const float dh = sqrtf(sh) - sqrtf(gh);
    const float wh = 5.f * (dw * dw + dh * dh);

    float cls = 0.f;
#pragma unroll
    for (int k = 0; k < 10; ++k) {                  // channels 10..29
        const float2 pd = *(const float2*)(pp + 10 + 2 * k);
        const float2 ld = *(const float2*)(lp + 10 + 2 * k);
        const float dx = pd.x - ld.x;
        const float dy = pd.y - ld.y;
        cls += dx * dx + dy * dy;
    }

    v0 += center * mask;
    v1 += wh * mask;
    v2 += imax * mask;
    v3 += imin * mask;
    v4 += cls * mask;
}

// Pipelined predicated staging (best-known configuration, R8):
//   - lab tiles double-buffered in LDS; tile t+NB staged FULLY (line-granular
//     HBM billing makes sub-line lab skipping worthless — R10 measured).
//   - mask bits for tile t balloted ONE ITERATION AHEAD from the staged lab
//     tile (no serializing labels->ballot->pred chain inside an iteration).
//   - pred tile t staged PREDICATED per 16B chunk by those bits (~49% of pred
//     chunks skipped at p=0.3; HBM fetch 94->71 MB measured).
//   All global loads of an iteration issue in one dependency-free burst.
__global__ __launch_bounds__(TPB) void yolo_partial(const float* __restrict__ pred,
                                                    const float* __restrict__ lab,
                                                    float* __restrict__ partial,
                                                    int n_cells) {
    __shared__ float sp[TW];                 // pred tile (7.68 KB)
    __shared__ float sl[2][TW];              // lab tiles cur/nxt (15.36 KB)
    __shared__ unsigned long long sbits;     // mask bits of the "current" tile
    __shared__ float red[5][TPB / 64];

    const int tid  = threadIdx.x;
    const int wave = tid >> 6;
    const int lane = tid & 63;
    const int bid  = blockIdx.x;
    const int NB   = gridDim.x;
    const int nt   = n_cells / TILE;         // 12544 full tiles

    // This thread's two float4-chunk indices within a 480-chunk array tile.
    const int  idx0 = tid;                   // always < 480
    const int  idx1 = TPB + tid;             // < 480 iff tid < 224
    const bool has1 = (idx1 < TF4);

    // Chunk -> covering-cell ids (compile-time divides by 30 -> magic mul).
    const int c00 = (4 * idx0) / NCH, c01 = (4 * idx0 + 3) / NCH;
    const int c10 = has1 ? (4 * idx1) / NCH : 0;
    const int c11 = has1 ? (4 * idx1 + 3) / NCH : 0;

    float v0 = 0.f, v1 = 0.f, v2 = 0.f, v3 = 0.f, v4 = 0.f;

    int cur = 0;
    unsigned long long bits = 0;

    if (bid < nt) {
        // ---- prologue: stage lab tile `bid` fully, ballot its masks ----
        {
            const size_t gbase = (size_t)bid * TW;
            float4 l0 = *(const float4*)(lab + gbase + (size_t)idx0 * 4);
            float4 l1;
            if (has1) l1 = *(const float4*)(lab + gbase + (size_t)idx1 * 4);
            *(float4*)(&sl[0][idx0 * 4]) = l0;
            if (has1) *(float4*)(&sl[0][idx1 * 4]) = l1;
        }
        __syncthreads();
        {
            const unsigned long long b =
                __ballot(tid < TILE && sl[0][tid * NCH] != 0.f);
            if (tid == 0) sbits = b;     // wave 0's ballot = the 64 cell bits
        }
        __syncthreads();
        bits = sbits;

        for (int t = bid; t < nt; t += NB) {
            const int  nxt = cur ^ 1;
            const bool have_next = (t + NB < nt);
            const size_t gbase = (size_t)t * TW;

            // ---- issue ALL loads for this iteration, dependency-free ----
            float4 p0, p1, l0, l1;
            const bool need0 = (((bits >> c00) & 1ull) | ((bits >> c01) & 1ull));
            const bool need1 = has1 &&
                               (((bits >> c10) & 1ull) | ((bits >> c11) & 1ull));
            if (need0) p0 = *(const float4*)(pred + gbase + (size_t)idx0 * 4);
            if (need1) p1 = *(const float4*)(pred + gbase + (size_t)idx1 * 4);
            if (have_next) {
                const size_t nbase = (size_t)(t + NB) * TW;
                l0 = *(const float4*)(lab + nbase + (size_t)idx0 * 4);
                if (has1) l1 = *(const float4*)(lab + nbase + (size_t)idx1 * 4);
            }

            // ---- spill to LDS (compiler inserts precise vmcnt waits) ----
            if (need0) *(float4*)(&sp[idx0 * 4]) = p0;
            if (need1) *(float4*)(&sp[idx1 * 4]) = p1;
            if (have_next) {
                *(float4*)(&sl[nxt][idx0 * 4]) = l0;
                if (has1) *(float4*)(&sl[nxt][idx1 * 4]) = l1;
            }
            __syncthreads();

            // ---- compute tile t (one cell per lane of wave 0) ----
            if (tid < TILE)
                cell_loss(sp + tid * NCH, &sl[cur][tid * NCH],
                          v0, v1, v2, v3, v4);

            // ---- ballot next tile's masks from the just-staged lab ----
            unsigned long long b = 0;
            if (have_next)
                b = __ballot(tid < TILE && sl[nxt][tid * NCH] != 0.f);
            if (tid == 0) sbits = b;
            __syncthreads();
            bits = sbits;
            cur = nxt;
        }
    }

    // Remainder cells — direct from global (never taken: 802816 % 64 == 0).
    const int rem_start = nt * TILE;
    if (bid == 0 && rem_start < n_cells) {
        for (int c = rem_start + tid; c < n_cells; c += TPB) {
            cell_loss(pred + (size_t)c * NCH, lab + (size_t)c * NCH,
                      v0, v1, v2, v3, v4);
        }
    }

    // ---- block reduction ----
#pragma unroll
    for (int off = 32; off > 0; off >>= 1) {
        v0 += __shfl_down(v0, off);
        v1 += __shfl_down(v1, off);
        v2 += __shfl_down(v2, off);
        v3 += __shfl_down(v3, off);
        v4 += __shfl_down(v4, off);
    }
    if (lane == 0) {
        red[0][wave] = v0;
        red[1][wave] = v1;
        red[2][wave] = v2;
        red[3][wave] = v3;
        red[4][wave] = v4;
    }
    __syncthreads();
    if (tid < 5) {
        float sacc = 0.f;
#pragma unroll
        for (int w = 0; w < TPB / 64; ++w) sacc += red[tid][w];
        partial[(size_t)bid * 5 + tid] = sacc;
    }
}

// Reduce n_blocks x 5 partials -> out[0..4]. One block.
__global__ __launch_bounds__(256) void final_reduce(const float* __restrict__ partial,
                                                    float* __restrict__ out,
                                                    int n_blocks) {
    __shared__ float red[5][4];
    const int tid = threadIdx.x;
    float v0 = 0.f, v1 = 0.f, v2 = 0.f, v3 = 0.f, v4 = 0.f;
    for (int b = tid; b < n_blocks; b += 256) {
        const float* p = partial + (size_t)b * 5;
        v0 += p[0]; v1 += p[1]; v2 += p[2]; v3 += p[3]; v4 += p[4];
    }
#pragma unroll
    for (int off = 32; off > 0; off >>= 1) {
        v0 += __shfl_down(v0, off);
        v1 += __shfl_down(v1, off);
        v2 += __shfl_down(v2, off);
        v3 += __shfl_down(v3, off);
        v4 += __shfl_down(v4, off);
    }
    const int wave = tid >> 6;
    const int lane = tid & 63;
    if (lane == 0) {
        red[0][wave] = v0;
        red[1][wave] = v1;
        red[2][wave] = v2;
        red[3][wave] = v3;
        red[4][wave] = v4;
    }
    __syncthreads();
    if (tid < 5) {
        float sacc = 0.f;
#pragma unroll
        for (int w = 0; w < 4; ++w) sacc += red[tid][w];
        out[tid] = sacc;
    }
}

extern "C" void kernel_launch(void* const* d_in, const int* in_sizes, int n_in,
                              void* d_out, int out_size, void* d_ws, size_t ws_size,
                              hipStream_t stream) {
    const float* pred = (const float*)d_in[0];
    const float* lab  = (const float*)d_in[1];
    float* out = (float*)d_out;
    float* partial = (float*)d_ws;                 // 1536*5*4 = 30,720 B

    const int n_cells = in_sizes[0] / NCH;         // 802816

    hipLaunchKernelGGL(yolo_partial, dim3(NBLK), dim3(TPB), 0, stream,
                       pred, lab, partial, n_cells);
    hipLaunchKernelGGL(final_reduce, dim3(1), dim3(256), 0, stream,
                       partial, out, NBLK);
}